// Round 6
// baseline (6632.107 us; speedup 1.0000x reference)
//
#include <hip/hip_runtime.h>

typedef unsigned short u16;
typedef unsigned int u32;
typedef unsigned long long u64;
typedef __attribute__((ext_vector_type(8))) short bf16x8;   // 8 bf16 = 4 VGPRs
typedef __attribute__((ext_vector_type(4))) float f32x4;
typedef __attribute__((ext_vector_type(4))) u32 u32x4;

namespace {
constexpr int kT = 1024, kI = 64, kH = 512, kO = 24;
constexpr int kBH = 64 * kH;            // 32768 elems per h buffer (bf16)
constexpr int kGiBuf = 98304;           // floats per gi2 buffer (64b x 1536)
constexpr int kGiTile = 768;            // floats per gi2 tile (3g x 16u x 16b)
// ws map (bytes): h1 slab @0 (4x65536), h2 @262144, gi2 @524288 (4x393216 f32),
// ctl @2097152. ctl ints: [0..127] fgi[u2*4+B], [128..255] fh2[U*4+B],
// [256..259] fout1[B], [260..263] fout2[B].
}

__device__ __forceinline__ u16 f2bf(float f) {   // round-to-nearest-even
  union { float f; u32 u; } c; c.f = f;
  u32 u = c.u + 0x7FFFu + ((c.u >> 16) & 1u);
  return (u16)(u >> 16);
}
__device__ __forceinline__ float sigf(float x) { return 1.0f / (1.0f + __expf(-x)); }
__device__ __forceinline__ float tanhf_(float x) {
  float e = __expf(2.0f * x); return 1.0f - 2.0f / (e + 1.0f);  // safe at +-inf
}
__device__ __forceinline__ bf16x8 cvt8(const float* p) {  // fp32x8 -> bf16x8 (RNE)
  const float4 f0 = *reinterpret_cast<const float4*>(p);
  const float4 f1 = *reinterpret_cast<const float4*>(p + 4);
  bf16x8 r;
  r[0] = (short)f2bf(f0.x); r[1] = (short)f2bf(f0.y);
  r[2] = (short)f2bf(f0.z); r[3] = (short)f2bf(f0.w);
  r[4] = (short)f2bf(f1.x); r[5] = (short)f2bf(f1.y);
  r[6] = (short)f2bf(f1.z); r[7] = (short)f2bf(f1.w);
  return r;
}
__device__ __forceinline__ f32x4 mfma(bf16x8 a, bf16x8 b, f32x4 c) {
  return __builtin_amdgcn_mfma_f32_16x16x32_bf16(a, b, c, 0, 0, 0);
}
__device__ __forceinline__ int ldflag(const int* s, int i) {
  return __hip_atomic_load(&s[i], __ATOMIC_RELAXED, __HIP_MEMORY_SCOPE_AGENT);
}
__device__ __forceinline__ void stflag(int* s, int i, int v) {
  __hip_atomic_store(&s[i], v, __ATOMIC_RELAXED, __HIP_MEMORY_SCOPE_AGENT);
}
// tick tag (k mod 3): bf16 granules carry bits in elems 0,1 LSBs; gi2 f32
// granules carry bits in LSBs of f0,f1 (and f2,f3). (buf=k&3, tag=k%3)
// repeats every 12 ticks; distance-4 certs cap skew at 4 => unique.
__device__ __forceinline__ u32 pat3(int t3) {
  return ((u32)t3 & 1u) | ((((u32)t3 >> 1) & 1u) << 16);
}
__device__ __forceinline__ bool tagok1(const bf16x8& v, u32 pat) {
  union { bf16x8 v; u32 u[4]; } t; t.v = v;
  return ((t.u[0] & 0x10001u) == pat) && ((t.u[2] & 0x10001u) == pat);
}
__device__ __forceinline__ bool tags16(const bf16x8* ch, u32 pat) {
  bool ok = true;
#pragma unroll
  for (int c = 0; c < 16; ++c) ok = ok && tagok1(ch[c], pat);
  return ok;
}
__device__ __forceinline__ bool gtagok(const u32x4& w, u32 a, u32 b) {
  return ((w[0] & 1u) == a) && ((w[1] & 1u) == b) &&
         ((w[2] & 1u) == a) && ((w[3] & 1u) == b);
}
// sentinel poll: one 8B agent load per lane, 64 lanes span 32 producer tiles
// x 2 batches. Cheap (512 B/wave/iter); gates the fat fetch.
__device__ __forceinline__ void pollh(const u16* ps, u32 pat) {
  int sp = 0;
  for (;;) {
    u64 g = __hip_atomic_load((const u64*)ps, __ATOMIC_RELAXED, __HIP_MEMORY_SCOPE_AGENT);
    if (__all(((u32)g & 0x10001u) == pat)) break;
    if ((++sp & 7) == 7) __builtin_amdgcn_s_sleep(1);
  }
}
// h2 dual sentinel: h2[k-1] granule + gi2[k] granule, one asm, one drain.
__device__ __forceinline__ void poll2(const u16* ps, u32 pat,
                                      const float* pg, u32 a, u32 b) {
  int sp = 0;
  for (;;) {
    u64 h, g;
    asm volatile(
      "global_load_dwordx2 %0, %2, off sc0 sc1\n\t"
      "global_load_dwordx2 %1, %3, off sc0 sc1\n\t"
      "s_waitcnt vmcnt(0)"
      : "=&v"(h), "=&v"(g) : "v"(ps), "v"(pg) : "memory");
    bool ok = (((u32)h & 0x10001u) == pat) &&
              (((u32)g & 1u) == a) && (((u32)(g >> 32) & 1u) == b);
    if (__all(ok)) break;
    if ((++sp & 7) == 7) __builtin_amdgcn_s_sleep(1);
  }
}
// PIPELINED 16-chunk fetch: full 512-dim h row-slab for 16 batches (16 KB/
// wave), 16 loads + ONE vmcnt drain (R5-proven pattern, single asm so no
// use-before-waitcnt hazard).
union V16 { u32x4 u; bf16x8 v; };
__device__ __forceinline__ void fetch16(const u16* p, bf16x8* ch) {
  u32x4 t0,t1,t2,t3,t4,t5,t6,t7,t8,t9,t10,t11,t12,t13,t14,t15;
  asm volatile(
    "global_load_dwordx4 %0, %16, off sc0 sc1\n\t"
    "global_load_dwordx4 %1, %16, off offset:64 sc0 sc1\n\t"
    "global_load_dwordx4 %2, %16, off offset:128 sc0 sc1\n\t"
    "global_load_dwordx4 %3, %16, off offset:192 sc0 sc1\n\t"
    "global_load_dwordx4 %4, %16, off offset:256 sc0 sc1\n\t"
    "global_load_dwordx4 %5, %16, off offset:320 sc0 sc1\n\t"
    "global_load_dwordx4 %6, %16, off offset:384 sc0 sc1\n\t"
    "global_load_dwordx4 %7, %16, off offset:448 sc0 sc1\n\t"
    "global_load_dwordx4 %8, %16, off offset:512 sc0 sc1\n\t"
    "global_load_dwordx4 %9, %16, off offset:576 sc0 sc1\n\t"
    "global_load_dwordx4 %10, %16, off offset:640 sc0 sc1\n\t"
    "global_load_dwordx4 %11, %16, off offset:704 sc0 sc1\n\t"
    "global_load_dwordx4 %12, %16, off offset:768 sc0 sc1\n\t"
    "global_load_dwordx4 %13, %16, off offset:832 sc0 sc1\n\t"
    "global_load_dwordx4 %14, %16, off offset:896 sc0 sc1\n\t"
    "global_load_dwordx4 %15, %16, off offset:960 sc0 sc1\n\t"
    "s_waitcnt vmcnt(0)"
    : "=&v"(t0), "=&v"(t1), "=&v"(t2), "=&v"(t3),
      "=&v"(t4), "=&v"(t5), "=&v"(t6), "=&v"(t7),
      "=&v"(t8), "=&v"(t9), "=&v"(t10), "=&v"(t11),
      "=&v"(t12), "=&v"(t13), "=&v"(t14), "=&v"(t15)
    : "v"(p) : "memory");
  V16 u;
  u.u=t0; ch[0]=u.v;   u.u=t1; ch[1]=u.v;   u.u=t2; ch[2]=u.v;   u.u=t3; ch[3]=u.v;
  u.u=t4; ch[4]=u.v;   u.u=t5; ch[5]=u.v;   u.u=t6; ch[6]=u.v;   u.u=t7; ch[7]=u.v;
  u.u=t8; ch[8]=u.v;   u.u=t9; ch[9]=u.v;   u.u=t10; ch[10]=u.v; u.u=t11; ch[11]=u.v;
  u.u=t12; ch[12]=u.v; u.u=t13; ch[13]=u.v; u.u=t14; ch[14]=u.v; u.u=t15; ch[15]=u.v;
}
__device__ __forceinline__ void fetchv16(const u16* p, u32 pat, bf16x8* ch) {
  int sp = 0;
  for (;;) {
    fetch16(p, ch);
    if (__all(tags16(ch, pat))) break;
    if ((++sp & 7) == 7) __builtin_amdgcn_s_sleep(1);
  }
  __asm__ volatile("" ::: "memory");
}
// h2 combined fetch: 16 h-chunks + 3 gi2 gate-vectors, one drain.
__device__ __forceinline__ void fetch19(const u16* ph, const float* pg,
                                        bf16x8* ch, u32x4* gv) {
  u32x4 t0,t1,t2,t3,t4,t5,t6,t7,t8,t9,t10,t11,t12,t13,t14,t15,g0,g1,g2;
  asm volatile(
    "global_load_dwordx4 %0, %19, off sc0 sc1\n\t"
    "global_load_dwordx4 %1, %19, off offset:64 sc0 sc1\n\t"
    "global_load_dwordx4 %2, %19, off offset:128 sc0 sc1\n\t"
    "global_load_dwordx4 %3, %19, off offset:192 sc0 sc1\n\t"
    "global_load_dwordx4 %4, %19, off offset:256 sc0 sc1\n\t"
    "global_load_dwordx4 %5, %19, off offset:320 sc0 sc1\n\t"
    "global_load_dwordx4 %6, %19, off offset:384 sc0 sc1\n\t"
    "global_load_dwordx4 %7, %19, off offset:448 sc0 sc1\n\t"
    "global_load_dwordx4 %8, %19, off offset:512 sc0 sc1\n\t"
    "global_load_dwordx4 %9, %19, off offset:576 sc0 sc1\n\t"
    "global_load_dwordx4 %10, %19, off offset:640 sc0 sc1\n\t"
    "global_load_dwordx4 %11, %19, off offset:704 sc0 sc1\n\t"
    "global_load_dwordx4 %12, %19, off offset:768 sc0 sc1\n\t"
    "global_load_dwordx4 %13, %19, off offset:832 sc0 sc1\n\t"
    "global_load_dwordx4 %14, %19, off offset:896 sc0 sc1\n\t"
    "global_load_dwordx4 %15, %19, off offset:960 sc0 sc1\n\t"
    "global_load_dwordx4 %16, %20, off sc0 sc1\n\t"
    "global_load_dwordx4 %17, %20, off offset:1024 sc0 sc1\n\t"
    "global_load_dwordx4 %18, %20, off offset:2048 sc0 sc1\n\t"
    "s_waitcnt vmcnt(0)"
    : "=&v"(t0), "=&v"(t1), "=&v"(t2), "=&v"(t3),
      "=&v"(t4), "=&v"(t5), "=&v"(t6), "=&v"(t7),
      "=&v"(t8), "=&v"(t9), "=&v"(t10), "=&v"(t11),
      "=&v"(t12), "=&v"(t13), "=&v"(t14), "=&v"(t15),
      "=&v"(g0), "=&v"(g1), "=&v"(g2)
    : "v"(ph), "v"(pg) : "memory");
  V16 u;
  u.u=t0; ch[0]=u.v;   u.u=t1; ch[1]=u.v;   u.u=t2; ch[2]=u.v;   u.u=t3; ch[3]=u.v;
  u.u=t4; ch[4]=u.v;   u.u=t5; ch[5]=u.v;   u.u=t6; ch[6]=u.v;   u.u=t7; ch[7]=u.v;
  u.u=t8; ch[8]=u.v;   u.u=t9; ch[9]=u.v;   u.u=t10; ch[10]=u.v; u.u=t11; ch[11]=u.v;
  u.u=t12; ch[12]=u.v; u.u=t13; ch[13]=u.v; u.u=t14; ch[14]=u.v; u.u=t15; ch[15]=u.v;
  gv[0]=g0; gv[1]=g1; gv[2]=g2;
}
// tagged h store: 4 bf16 + 2 tag bits, ONE agent-scope atomic 8B store
__device__ __forceinline__ void st_h(u16* p, const float* h, int t3) {
  u16 a = (u16)((f2bf(h[0]) & ~1u) | ((u32)t3 & 1u));
  u16 b = (u16)((f2bf(h[1]) & ~1u) | (((u32)t3 >> 1) & 1u));
  u64 v = (u64)a | ((u64)b << 16) | ((u64)f2bf(h[2]) << 32) | ((u64)f2bf(h[3]) << 48);
  __hip_atomic_store((u64*)p, v, __ATOMIC_RELAXED, __HIP_MEMORY_SCOPE_AGENT);
}
// tagged gi2 store: f32x4 with tag bits in every mantissa LSB (err 2^-24)
__device__ __forceinline__ void st_gi(float* p, const f32x4& v, const float* bi, int t3) {
  u32 a = (u32)t3 & 1u, b = ((u32)t3 >> 1) & 1u;
  union { float f; u32 u; } c0, c1, c2, c3;
  c0.f = v[0] + bi[0]; c1.f = v[1] + bi[1];
  c2.f = v[2] + bi[2]; c3.f = v[3] + bi[3];
  u32x4 w;
  w[0] = (c0.u & ~1u) | a; w[1] = (c1.u & ~1u) | b;
  w[2] = (c2.u & ~1u) | a; w[3] = (c3.u & ~1u) | b;
  asm volatile("global_store_dwordx4 %0, %1, off sc0 sc1" :: "v"(p), "v"(w) : "memory");
}
// amortized distance-4 anti-dep throttle: consumers must have FETCHED tick
// k-4 before we overwrite it. Flags post right after fetch-verify.
__device__ __forceinline__ void throttle4(const int* f, int idx, bool act,
                                          int k, int& bound) {
  if (bound >= k - 4) return;
  int sp = 0;
  for (;;) {
    int v = act ? ldflag(f, idx) : 0x7fffffff;
    if (__all(v >= k - 4)) { bound = __all(v >= k) ? k : (k - 4); break; }
    if ((++sp & 3) == 3) __builtin_amdgcn_s_sleep(1);
  }
}

// WAVE-AUTONOMOUS dataflow (98 WGs x 256 thr, NO barriers, NO LDS):
// every wave owns a (16-unit, 16-batch) tile with full-K resident weights
// (192 VGPR) and runs poll->fetch->MFMA->act->store per tick independently.
//   wg  0..31 (128 waves): L1.  h1[k] = GRU(x[k], h1[k-1])     -> h1 slab
//   wg 32..63 (128 waves): GI2. gi2[k] = wih2 @ h1[k] + bih2   -> gi2 ring
//   wg 64..95 (128 waves): H2.  h2[k] = GRU(gi2[k], h2[k-1])   -> h2 slab
//   wg 96..97 (  8 waves): OUT. atomicAdd tanh partials into zeroed out
// Readiness = tags. Anti-deps: peers self-certify via the slab tags each
// wave already verifies (verify h[k-1] => all peers done reading h[k-2]);
// cross-stage readers post fgi/fh2/fout flags after fetch (distance-4).
// MFMA 16x16x32: A(w) m=l15,k=q*8+j ; B(h) n=l15,k=q*8+j ; C/D col=l15(batch),
// row=q*4+r(unit) -> activation is perfectly lane-local.
__global__ __launch_bounds__(256, 1) void stackgru(
    const float* __restrict__ x,
    const float* __restrict__ wih1, const float* __restrict__ whh1,
    const float* __restrict__ bih1, const float* __restrict__ bhh1,
    const float* __restrict__ wih2, const float* __restrict__ whh2,
    const float* __restrict__ bih2, const float* __restrict__ bhh2,
    const float* __restrict__ wo1, const float* __restrict__ bo1,
    const float* __restrict__ wo2, const float* __restrict__ bo2,
    float* __restrict__ out, u16* __restrict__ hbuf, float* __restrict__ gib,
    int* __restrict__ ctl)
{
  const int wg = blockIdx.x;
  const int tid = threadIdx.x;
  const int lane = tid & 63;
  const int w = tid >> 6;
  const int l15 = lane & 15;
  const int q = lane >> 4;
  u16* h1s = hbuf;
  u16* h2s = hbuf + 4 * kBH;
  const int sU = (lane & 31) * 16;      // sentinel: unit-elem of producer tile
  const int sB = (lane >> 5) * 15;      // sentinel: batch 0 / 15 within block

  if (wg < 32) {
    // ---------------- layer 1 (recurrence critical cycle) ----------------
    const int idx = wg * 4 + w, U0 = (idx & 31) * 16, B = idx >> 5;
    const int bb = B * 16 + l15;
    bf16x8 whf[3][16];                  // 192 VGPR resident w_hh1
#pragma unroll
    for (int g = 0; g < 3; ++g)
#pragma unroll
      for (int c = 0; c < 16; ++c)
        whf[g][c] = cvt8(whh1 + (size_t)(g * kH + U0 + l15) * kH + c * 32 + q * 8);
    bf16x8 aihf[3][2];
#pragma unroll
    for (int g = 0; g < 3; ++g)
#pragma unroll
      for (int c = 0; c < 2; ++c)
        aihf[g][c] = cvt8(wih1 + (size_t)(g * kH + U0 + l15) * kI + c * 32 + q * 8);
    float br[4], bz[4], bni[4], bnh[4], h1l[4];
#pragma unroll
    for (int r = 0; r < 4; ++r) {
      int u = U0 + q * 4 + r;
      br[r]  = bih1[u]          + bhh1[u];
      bz[r]  = bih1[kH + u]     + bhh1[kH + u];
      bni[r] = bih1[2 * kH + u];
      bnh[r] = bhh1[2 * kH + u];
      h1l[r] = 0.0f;
    }
    const int thridx = (lane < 32) ? (lane * 4 + B) : (256 + B);
    const bool thract = (lane < 33);
    int bound = 0;
    for (int k = 1; k <= kT; ++k) {
      const int t3 = k % 3, t3p = (k - 1) % 3;
      const float* xs = x + ((size_t)bb * kT + (k - 1)) * kI + q * 8;
      bf16x8 xf0 = cvt8(xs), xf1 = cvt8(xs + 32);
      const u16* pb = h1s + ((k - 1) & 3) * kBH;
      pollh(pb + (size_t)(B * 16 + sB) * kH + sU, pat3(t3p));
      bf16x8 hch[16];
      fetchv16(pb + (size_t)bb * kH + q * 8, pat3(t3p), hch);
      f32x4 aR = {0,0,0,0}, aZ = {0,0,0,0}, aNh = {0,0,0,0}, aNi = {0,0,0,0};
#pragma unroll
      for (int c = 0; c < 16; ++c) {
        aR  = mfma(whf[0][c], hch[c], aR);
        aZ  = mfma(whf[1][c], hch[c], aZ);
        aNh = mfma(whf[2][c], hch[c], aNh);
      }
      aR  = mfma(aihf[0][0], xf0, aR);  aR  = mfma(aihf[0][1], xf1, aR);
      aZ  = mfma(aihf[1][0], xf0, aZ);  aZ  = mfma(aihf[1][1], xf1, aZ);
      aNi = mfma(aihf[2][0], xf0, aNi); aNi = mfma(aihf[2][1], xf1, aNi);
      throttle4(ctl, thridx, thract, k, bound);   // gi2 + OUT readers of h1
      float hnew[4];
#pragma unroll
      for (int r = 0; r < 4; ++r) {
        float rr = sigf(aR[r] + br[r]);
        float zz = sigf(aZ[r] + bz[r]);
        float nn = tanhf_(aNi[r] + bni[r] + rr * (aNh[r] + bnh[r]));
        float h  = (1.0f - zz) * nn + zz * h1l[r];
        h1l[r] = h; hnew[r] = h;
      }
      st_h(h1s + (k & 3) * kBH + (size_t)bb * kH + U0 + q * 4, hnew, t3);
    }
  } else if (wg < 64) {
    // ---------------- gi2 stage (forward dataflow) ----------------
    const int idx = (wg - 32) * 4 + w, u2 = idx & 31, U0 = u2 * 16, B = idx >> 5;
    const int bb = B * 16 + l15;
    bf16x8 whf[3][16];                  // wih2
#pragma unroll
    for (int g = 0; g < 3; ++g)
#pragma unroll
      for (int c = 0; c < 16; ++c)
        whf[g][c] = cvt8(wih2 + (size_t)(g * kH + U0 + l15) * kH + c * 32 + q * 8);
    float bi[3][4];
#pragma unroll
    for (int g = 0; g < 3; ++g)
#pragma unroll
      for (int r = 0; r < 4; ++r) bi[g][r] = bih2[g * kH + U0 + q * 4 + r];
    const int fidx = u2 * 4 + B;
    int bound = 0;
    for (int k = 1; k <= kT; ++k) {
      const int t3 = k % 3;
      const u16* pb = h1s + (k & 3) * kBH;
      pollh(pb + (size_t)(B * 16 + sB) * kH + sU, pat3(t3));
      bf16x8 hch[16];
      fetchv16(pb + (size_t)bb * kH + q * 8, pat3(t3), hch);
      if (lane == 0) stflag(ctl, fidx, k);        // h1[k] consumed (fgi)
      f32x4 a0 = {0,0,0,0}, a1 = {0,0,0,0}, a2 = {0,0,0,0};
#pragma unroll
      for (int c = 0; c < 16; ++c) {
        a0 = mfma(whf[0][c], hch[c], a0);
        a1 = mfma(whf[1][c], hch[c], a1);
        a2 = mfma(whf[2][c], hch[c], a2);
      }
      throttle4(ctl, 128 + fidx, true, k, bound); // h2 reader of gi2
      float* tp = gib + (size_t)(k & 3) * kGiBuf + (size_t)(B * 32 + u2) * kGiTile
                  + l15 * 16 + q * 4;
      st_gi(tp,       a0, bi[0], t3);
      st_gi(tp + 256, a1, bi[1], t3);
      st_gi(tp + 512, a2, bi[2], t3);
    }
  } else if (wg < 96) {
    // ---------------- layer 2 recurrence ----------------
    const int idx = (wg - 64) * 4 + w, U = idx & 31, U0 = U * 16, B = idx >> 5;
    const int bb = B * 16 + l15;
    bf16x8 whf[3][16];                  // whh2
#pragma unroll
    for (int g = 0; g < 3; ++g)
#pragma unroll
      for (int c = 0; c < 16; ++c)
        whf[g][c] = cvt8(whh2 + (size_t)(g * kH + U0 + l15) * kH + c * 32 + q * 8);
    float br2[4], bz2[4], bnh2[4], h2l[4];
#pragma unroll
    for (int r = 0; r < 4; ++r) {
      int u = U0 + q * 4 + r;
      br2[r]  = bhh2[u];
      bz2[r]  = bhh2[kH + u];
      bnh2[r] = bhh2[2 * kH + u];
      h2l[r] = 0.0f;
    }
    const int fidx = U * 4 + B;
    int bound = 0;
    for (int k = 1; k <= kT; ++k) {
      const int t3 = k % 3, t3p = (k - 1) % 3;
      const u32 ga = (u32)t3 & 1u, gb = ((u32)t3 >> 1) & 1u;
      const u16* pb = h2s + ((k - 1) & 3) * kBH;
      const float* tp = gib + (size_t)(k & 3) * kGiBuf
                        + (size_t)(B * 32 + U) * kGiTile + l15 * 16 + q * 4;
      poll2(pb + (size_t)(B * 16 + sB) * kH + sU, pat3(t3p), tp, ga, gb);
      bf16x8 hch[16]; u32x4 gv[3];
      int sp = 0;
      for (;;) {
        fetch19(pb + (size_t)bb * kH + q * 8, tp, hch, gv);
        bool ok = tags16(hch, pat3(t3p)) && gtagok(gv[0], ga, gb) &&
                  gtagok(gv[1], ga, gb) && gtagok(gv[2], ga, gb);
        if (__all(ok)) break;
        if ((++sp & 7) == 7) __builtin_amdgcn_s_sleep(1);
      }
      __asm__ volatile("" ::: "memory");
      if (lane == 0) stflag(ctl, 128 + fidx, k);  // gi2[k]+h2[k-1] consumed
      f32x4 aR = {0,0,0,0}, aZ = {0,0,0,0}, aNh = {0,0,0,0};
#pragma unroll
      for (int c = 0; c < 16; ++c) {
        aR  = mfma(whf[0][c], hch[c], aR);
        aZ  = mfma(whf[1][c], hch[c], aZ);
        aNh = mfma(whf[2][c], hch[c], aNh);
      }
      throttle4(ctl, 260 + B, true, k, bound);    // OUT reader of h2
      union { u32x4 u; f32x4 f; } g0, g1, g2;
      g0.u = gv[0]; g1.u = gv[1]; g2.u = gv[2];
      float hnew[4];
#pragma unroll
      for (int r = 0; r < 4; ++r) {
        float rr = sigf(g0.f[r] + aR[r] + br2[r]);
        float zz = sigf(g1.f[r] + aZ[r] + bz2[r]);
        float nn = tanhf_(g2.f[r] + rr * (aNh[r] + bnh2[r]));
        float h  = (1.0f - zz) * nn + zz * h2l[r];
        h2l[r] = h; hnew[r] = h;
      }
      st_h(h2s + (k & 3) * kBH + (size_t)bb * kH + U0 + q * 4, hnew, t3);
    }
  } else {
    // ---------------- output head (atomicAdd partials) ----------------
    const int idx = (wg - 96) * 4 + w, B = idx >> 1, mat = idx & 1;
    const int bb = B * 16 + l15;
    const u16* slab = mat ? h2s : h1s;
    const float* wsel = mat ? wo2 : wo1;
    const float* bsel = mat ? bo2 : bo1;
    bf16x8 zf = {0,0,0,0,0,0,0,0};
    bf16x8 wof[2][16];
#pragma unroll
    for (int t = 0; t < 2; ++t)
#pragma unroll
      for (int c = 0; c < 16; ++c) {
        int row = t * 16 + l15;
        wof[t][c] = (row < kO) ? cvt8(wsel + (size_t)row * kH + c * 32 + q * 8) : zf;
      }
    float bv[2][4];
#pragma unroll
    for (int t = 0; t < 2; ++t)
#pragma unroll
      for (int r = 0; r < 4; ++r) {
        int o = t * 16 + q * 4 + r;
        bv[t][r] = (o < kO) ? bsel[o] : 0.0f;
      }
    for (int k = 1; k <= kT; ++k) {
      const int t3 = k % 3;
      const u16* pb = slab + (k & 3) * kBH;
      pollh(pb + (size_t)(B * 16 + sB) * kH + sU, pat3(t3));
      bf16x8 hch[16];
      fetchv16(pb + (size_t)bb * kH + q * 8, pat3(t3), hch);
      if (lane == 0) stflag(ctl, (mat ? 260 : 256) + B, k);
      f32x4 a0 = {0,0,0,0}, a1 = {0,0,0,0};
#pragma unroll
      for (int c = 0; c < 16; ++c) {
        a0 = mfma(wof[0][c], hch[c], a0);
        a1 = mfma(wof[1][c], hch[c], a1);
      }
      float* ob = out + ((size_t)bb * kT + (k - 1)) * kO;
#pragma unroll
      for (int r = 0; r < 4; ++r) {
        int o0 = q * 4 + r;
        atomicAdd(ob + o0, tanhf_(a0[r] + bv[0][r]));   // tile0 rows 0..15
        int o1 = 16 + q * 4 + r;
        if (o1 < kO) atomicAdd(ob + o1, tanhf_(a1[r] + bv[1][r]));
      }
    }
  }
}

extern "C" void kernel_launch(void* const* d_in, const int* in_sizes, int n_in,
                              void* d_out, int out_size, void* d_ws, size_t ws_size,
                              hipStream_t stream) {
  (void)in_sizes; (void)n_in; (void)out_size; (void)ws_size;
  // zero slabs + gi2 + ctl; invalid-tag init (0x01) for buf 3 of each ring
  // (first occupant of buf3 has tag 0 == zero-init -- the R8-class hazard)
  hipMemsetAsync(d_ws, 0, 2097152u + 4096u, stream);
  hipMemsetAsync((char*)d_ws + 3u * 65536u, 0x01, 65536u, stream);            // h1 buf3
  hipMemsetAsync((char*)d_ws + 262144u + 3u * 65536u, 0x01, 65536u, stream);  // h2 buf3
  hipMemsetAsync((char*)d_ws + 524288u + 3u * 393216u, 0x01, 393216u, stream); // gi2 buf3
  hipMemsetAsync(d_out, 0, (size_t)64 * 1024 * 24 * sizeof(float), stream);   // atomicAdd base
  const float* x    = (const float*)d_in[0];
  const float* wih1 = (const float*)d_in[1];
  const float* whh1 = (const float*)d_in[2];
  const float* bih1 = (const float*)d_in[3];
  const float* bhh1 = (const float*)d_in[4];
  const float* wih2 = (const float*)d_in[5];
  const float* whh2 = (const float*)d_in[6];
  const float* bih2 = (const float*)d_in[7];
  const float* bhh2 = (const float*)d_in[8];
  const float* wo1  = (const float*)d_in[9];
  const float* bo1  = (const float*)d_in[10];
  const float* wo2  = (const float*)d_in[11];
  const float* bo2  = (const float*)d_in[12];
  float* out  = (float*)d_out;
  u16* hbuf   = (u16*)d_ws;
  float* gib  = (float*)((char*)d_ws + 524288u);
  int* ctl    = (int*)((char*)d_ws + 2097152u);
  stackgru<<<dim3(98), dim3(256), 0, stream>>>(
      x, wih1, whh1, bih1, bhh1, wih2, whh2, bih2, bhh2,
      wo1, bo1, wo2, bo2, out, hbuf, gib, ctl);
}

// Round 7
// 5014.360 us; speedup vs baseline: 1.3226x; 1.3226x over previous
//
#include <hip/hip_runtime.h>

typedef unsigned short u16;
typedef unsigned int u32;
typedef unsigned long long u64;
typedef __attribute__((ext_vector_type(8))) short bf16x8;   // 8 bf16 = 4 VGPRs
typedef __attribute__((ext_vector_type(4))) float f32x4;
typedef __attribute__((ext_vector_type(4))) u32 u32x4;

namespace {
constexpr int kT = 1024, kI = 64, kH = 512, kO = 24;
constexpr int kBH = 64 * kH;                  // 32768 elems per h buffer (bf16)
constexpr int kNWG = 100;                     // 32 L1 + 64 L2 + 4 OUT
// h1: 4 bufs @0, h2: 4 bufs after (k mod 4), tags k mod 3, buf3 invalid-init
constexpr unsigned kBarOff = 8u * (unsigned)kBH * 2u;   // 524288 B
// ctl ints: [0..63] flagL2[j2] (j2 = ub2*4+g), [64..67] flagOUT[g]
}

__device__ __forceinline__ u16 f2bf(float f) {   // round-to-nearest-even
  union { float f; u32 u; } c; c.f = f;
  u32 u = c.u + 0x7FFFu + ((c.u >> 16) & 1u);
  return (u16)(u >> 16);
}
__device__ __forceinline__ float sigf(float x) { return 1.0f / (1.0f + __expf(-x)); }
__device__ __forceinline__ float tanhf_(float x) {
  float e = __expf(2.0f * x); return 1.0f - 2.0f / (e + 1.0f);  // safe at +-inf
}
__device__ __forceinline__ bf16x8 cvt8(const float* p) {  // fp32x8 -> bf16x8 (RNE)
  const float4 f0 = *reinterpret_cast<const float4*>(p);
  const float4 f1 = *reinterpret_cast<const float4*>(p + 4);
  bf16x8 r;
  r[0] = (short)f2bf(f0.x); r[1] = (short)f2bf(f0.y);
  r[2] = (short)f2bf(f0.z); r[3] = (short)f2bf(f0.w);
  r[4] = (short)f2bf(f1.x); r[5] = (short)f2bf(f1.y);
  r[6] = (short)f2bf(f1.z); r[7] = (short)f2bf(f1.w);
  return r;
}
__device__ __forceinline__ f32x4 mfma(bf16x8 a, bf16x8 b, f32x4 c) {
  return __builtin_amdgcn_mfma_f32_16x16x32_bf16(a, b, c, 0, 0, 0);
}
__device__ __forceinline__ int ldflag(const int* s, int i) {
  return __hip_atomic_load(&s[i], __ATOMIC_RELAXED, __HIP_MEMORY_SCOPE_AGENT);
}
__device__ __forceinline__ void stflag(int* s, int i, int v) {
  __hip_atomic_store(&s[i], v, __ATOMIC_RELAXED, __HIP_MEMORY_SCOPE_AGENT);
}
// PIPELINED agent fetch (R5-proven): all loads in one asm block, sc0 sc1
// (bypass L1+L2, coherent), ONE vmcnt drain => ~1 round trip per handshake.
union V16 { u32x4 u; bf16x8 v; };
__device__ __forceinline__ void fetch4(const u16* p, bf16x8* ch) {
  u32x4 a, b, c, d;
  asm volatile(
    "global_load_dwordx4 %0, %4, off sc0 sc1\n\t"
    "global_load_dwordx4 %1, %4, off offset:64 sc0 sc1\n\t"
    "global_load_dwordx4 %2, %4, off offset:128 sc0 sc1\n\t"
    "global_load_dwordx4 %3, %4, off offset:192 sc0 sc1\n\t"
    "s_waitcnt vmcnt(0)"
    : "=&v"(a), "=&v"(b), "=&v"(c), "=&v"(d) : "v"(p) : "memory");
  V16 t;
  t.u = a; ch[0] = t.v;  t.u = b; ch[1] = t.v;
  t.u = c; ch[2] = t.v;  t.u = d; ch[3] = t.v;
}
__device__ __forceinline__ void fetch8(const u16* p, bf16x8* ch) {
  u32x4 a, b, c, d, e, f, g2, h;
  asm volatile(
    "global_load_dwordx4 %0, %8, off sc0 sc1\n\t"
    "global_load_dwordx4 %1, %8, off offset:64 sc0 sc1\n\t"
    "global_load_dwordx4 %2, %8, off offset:128 sc0 sc1\n\t"
    "global_load_dwordx4 %3, %8, off offset:192 sc0 sc1\n\t"
    "global_load_dwordx4 %4, %8, off offset:256 sc0 sc1\n\t"
    "global_load_dwordx4 %5, %8, off offset:320 sc0 sc1\n\t"
    "global_load_dwordx4 %6, %8, off offset:384 sc0 sc1\n\t"
    "global_load_dwordx4 %7, %8, off offset:448 sc0 sc1\n\t"
    "s_waitcnt vmcnt(0)"
    : "=&v"(a), "=&v"(b), "=&v"(c), "=&v"(d),
      "=&v"(e), "=&v"(f), "=&v"(g2), "=&v"(h) : "v"(p) : "memory");
  V16 t;
  t.u = a; ch[0] = t.v;  t.u = b;  ch[1] = t.v;
  t.u = c; ch[2] = t.v;  t.u = d;  ch[3] = t.v;
  t.u = e; ch[4] = t.v;  t.u = f;  ch[5] = t.v;
  t.u = g2; ch[6] = t.v; t.u = h;  ch[7] = t.v;
}
// tick tag (k mod 3) in LSBs of bf16 elems 0,1 of each 8B granule.
// (buf = k mod 4, tag = k mod 3) repeat together every 12 ticks; distance-4
// throttle caps skew at 4 => no aliasing. (1,1) tag = INVALID buf3 init.
__device__ __forceinline__ u32 pat3(int t3) {
  return ((u32)t3 & 1u) | ((((u32)t3 >> 1) & 1u) << 16);
}
template<int N>
__device__ __forceinline__ bool tagsok(const bf16x8* ch, u32 pat) {
  bool ok = true;
#pragma unroll
  for (int c = 0; c < N; ++c) {
    union { bf16x8 v; u32 u[4]; } t; t.v = ch[c];
    ok = ok && ((t.u[0] & 0x10001u) == pat) && ((t.u[2] & 0x10001u) == pat);
  }
  return ok;
}
// tagged-data wait: phase 1 polls each lane's first 8B granule (cheap),
// phase 2 pipelined fetch + full tag verify (~1 iter). R5-proven.
template<int N>
__device__ __forceinline__ void dataD(const u16* p, u32 pat, bf16x8* ch) {
  int spins = 0;
  for (;;) {
    u64 g0 = __hip_atomic_load((const u64*)p, __ATOMIC_RELAXED, __HIP_MEMORY_SCOPE_AGENT);
    if (__all(((u32)g0 & 0x10001u) == pat)) break;
    if ((++spins & 3) == 3) __builtin_amdgcn_s_sleep(1);
  }
  spins = 0;
  for (;;) {
    if constexpr (N == 4) fetch4(p, ch); else fetch8(p, ch);
    if (__all(tagsok<N>(ch, pat))) break;
    if ((++spins & 7) == 7) __builtin_amdgcn_s_sleep(1);
  }
  __asm__ volatile("" ::: "memory");
}
// tagged h store: 4 bf16 + 2 tag bits, ONE agent-scope atomic 8B store
__device__ __forceinline__ void st_h(u16* p, const float* h, int t3) {
  u16 a = (u16)((f2bf(h[0]) & ~1u) | ((u32)t3 & 1u));
  u16 b = (u16)((f2bf(h[1]) & ~1u) | (((u32)t3 >> 1) & 1u));
  u64 v = (u64)a | ((u64)b << 16) | ((u64)f2bf(h[2]) << 32) | ((u64)f2bf(h[3]) << 48);
  __hip_atomic_store((u64*)p, v, __ATOMIC_RELAXED, __HIP_MEMORY_SCOPE_AGENT);
}
// amortized producer throttle: consumers' flags >= k-3 (i.e. they completed
// the tick-(k-3) fetch-verify) before overwriting tick k-4 in the mod-4 ring.
// A consumer's full-slab tag-verify transitively certifies every upstream
// producer stored that tick => peer producers are certified too (R5-proven).
__device__ __forceinline__ void throttle(const int* f, int idx, bool act,
                                         int k, int& bound) {
  if (bound >= k - 3) return;
  for (;;) {
    int v = act ? ldflag(f, idx) : 0x7fffffff;
    if (__all(v >= k - 3)) { bound = __all(v >= k) ? k : (k - 3); break; }
    __builtin_amdgcn_s_sleep(2);
  }
}

// FAT-WG roles (100 WGs x 256 thr; 4 batch-groups of 16). Coherent traffic
// per tick = #unit-blocks x slab: L1 8x64KB + L2 16x128KB + OUT = 2.6 MB
// (R5 was 6.5 MB -- the saturated agent-path is the theory's bottleneck).
//   wg  0..31 : L1. ub=wg>>2 (64-unit block), g=wg&3 (16-batch group).
//               4 waves = K-quarters of 512. x-GEMM (K=64) split across
//               kh1/kh2 (32 K each), n-gate x-partial via LDS redx.
//   wg 32..95 : L2. ub2 (32-unit block), g. 4 waves = quarters of combined
//               K=1024: kh0,1 = wih2@h1[k]; kh2,3 = whh2@h2[k-1].
//   wg 96..99 : OUT. g3 group. 4 waves = mat(wo1/wo2) x K-half. fin=mat0,kh0.
// flagL2[j2]/flagOUT[g] post AFTER the first barrier (all 4 waves' fetches
// tag-verified). Data readiness = tags; flags feed ONLY throttles.
// MFMA 16x16x32: A=weights m=unit(l15), B=h n=batch(l15), C/D col=l15(batch),
// row=q*4+r(unit) -> activations lane-local.
__global__ __launch_bounds__(256, 1) void stackgru(
    const float* __restrict__ x,
    const float* __restrict__ wih1, const float* __restrict__ whh1,
    const float* __restrict__ bih1, const float* __restrict__ bhh1,
    const float* __restrict__ wih2, const float* __restrict__ whh2,
    const float* __restrict__ bih2, const float* __restrict__ bhh2,
    const float* __restrict__ wo1, const float* __restrict__ bo1,
    const float* __restrict__ wo2, const float* __restrict__ bo2,
    float* __restrict__ out, u16* __restrict__ hbuf, int* __restrict__ ctl)
{
  __shared__ float red[3][3][4][64][4];   // 36 KB: [slot][gate][m][lane][r]
  __shared__ float redx[2][4][64][4];     // 8 KB: x n-gate partials (L1)
  __shared__ float sbias[4][64];          // staged biases
  const int wg = blockIdx.x;
  const int tid = threadIdx.x;
  const int lane = tid & 63;
  const int w = tid >> 6;                 // wave 0..3
  const int l15 = lane & 15;
  const int q = lane >> 4;

  u16* h1b = hbuf;                        // 4 * kBH
  u16* h2b = hbuf + 4 * kBH;              // 4 * kBH

  if (wg < 32) {
    // ---------------- layer 1 ----------------
    const int ub = wg >> 2, g = wg & 3;
    const int U0 = ub * 64;
    const int bb = g * 16 + l15;
    const int kh = w;                     // K-quarter (0..3), 128 K each
    bf16x8 whf[3][4][4];                  // 192 VGPR resident w_hh1
#pragma unroll
    for (int gg = 0; gg < 3; ++gg)
#pragma unroll
      for (int m = 0; m < 4; ++m)
#pragma unroll
        for (int c = 0; c < 4; ++c)
          whf[gg][m][c] = cvt8(whh1 + (size_t)(gg * kH + U0 + m * 16 + l15) * kH
                               + (kh * 4 + c) * 32 + q * 8);
    const bool hasx = (kh == 1 || kh == 2);
    const int xch = kh - 1;               // x chunk 0/1 (K=64 total)
    bf16x8 aihf[3][4];                    // 48 VGPR (kh1/kh2 only)
    if (hasx)
#pragma unroll
      for (int gg = 0; gg < 3; ++gg)
#pragma unroll
        for (int m = 0; m < 4; ++m)
          aihf[gg][m] = cvt8(wih1 + (size_t)(gg * kH + U0 + m * 16 + l15) * kI
                             + xch * 32 + q * 8);
    if (tid < 64) {                       // stage biases once
      int u = U0 + tid;
      sbias[0][tid] = bih1[u]          + bhh1[u];
      sbias[1][tid] = bih1[kH + u]     + bhh1[kH + u];
      sbias[2][tid] = bih1[2 * kH + u];
      sbias[3][tid] = bhh1[2 * kH + u];
    }
    float h1l[4][4];                      // fp32 master h1 (kh0 wave)
#pragma unroll
    for (int m = 0; m < 4; ++m)
#pragma unroll
      for (int r = 0; r < 4; ++r) h1l[m][r] = 0.0f;
    __syncthreads();
    // throttle watch (kh0): lanes 0..15 = flagL2 of group, lane 16 = flagOUT
    const int thridx = (lane < 16) ? (lane * 4 + g) : (64 + g);
    const bool thract = (lane < 17);
    int bound = 0;
    for (int k = 1; k <= kT; ++k) {
      const int t3 = k % 3, t3p = (k - 1) % 3;
      bf16x8 xf;
      if (hasx)
        xf = cvt8(x + ((size_t)bb * kT + (k - 1)) * kI + xch * 32 + q * 8);
      bf16x8 ch[4];
      dataD<4>(h1b + ((k - 1) & 3) * kBH + (size_t)bb * kH + kh * 128 + q * 8,
               pat3(t3p), ch);
      f32x4 aR[4], aZ[4], aN[4];
#pragma unroll
      for (int m = 0; m < 4; ++m) { aR[m] = {0,0,0,0}; aZ[m] = {0,0,0,0}; aN[m] = {0,0,0,0}; }
#pragma unroll
      for (int m = 0; m < 4; ++m)
#pragma unroll
        for (int c = 0; c < 4; ++c) {
          aR[m] = mfma(whf[0][m][c], ch[c], aR[m]);
          aZ[m] = mfma(whf[1][m][c], ch[c], aZ[m]);
          aN[m] = mfma(whf[2][m][c], ch[c], aN[m]);
        }
      if (hasx) {
        f32x4 xN[4];
#pragma unroll
        for (int m = 0; m < 4; ++m) xN[m] = {0,0,0,0};
#pragma unroll
        for (int m = 0; m < 4; ++m) {
          aR[m] = mfma(aihf[0][m], xf, aR[m]);   // r,z: fold x into h-accum
          aZ[m] = mfma(aihf[1][m], xf, aZ[m]);
          xN[m] = mfma(aihf[2][m], xf, xN[m]);   // n_i must stay separate
        }
#pragma unroll
        for (int m = 0; m < 4; ++m)
#pragma unroll
          for (int r = 0; r < 4; ++r) redx[xch][m][lane][r] = xN[m][r];
      }
      if (kh != 0) {
#pragma unroll
        for (int m = 0; m < 4; ++m)
#pragma unroll
          for (int r = 0; r < 4; ++r) {
            red[kh - 1][0][m][lane][r] = aR[m][r];
            red[kh - 1][1][m][lane][r] = aZ[m][r];
            red[kh - 1][2][m][lane][r] = aN[m][r];
          }
      } else {
        throttle(ctl, thridx, thract, k, bound);   // h1 anti-dep
      }
      __syncthreads();
      if (kh == 0) {
#pragma unroll
        for (int m = 0; m < 4; ++m) {
          float hnew[4];
#pragma unroll
          for (int r = 0; r < 4; ++r) {
            float sR = aR[m][r] + red[0][0][m][lane][r] + red[1][0][m][lane][r] + red[2][0][m][lane][r];
            float sZ = aZ[m][r] + red[0][1][m][lane][r] + red[1][1][m][lane][r] + red[2][1][m][lane][r];
            float sN = aN[m][r] + red[0][2][m][lane][r] + red[1][2][m][lane][r] + red[2][2][m][lane][r];
            float sNi = redx[0][m][lane][r] + redx[1][m][lane][r];
            int uu = m * 16 + q * 4 + r;
            float rr = sigf(sR + sbias[0][uu]);
            float zz = sigf(sZ + sbias[1][uu]);
            float nn = tanhf_(sNi + sbias[2][uu] + rr * (sN + sbias[3][uu]));
            float h  = (1.0f - zz) * nn + zz * h1l[m][r];
            h1l[m][r] = h; hnew[r] = h;
          }
          st_h(h1b + (k & 3) * kBH + (size_t)bb * kH + U0 + m * 16 + q * 4, hnew, t3);
        }
      }
      __syncthreads();                    // guards red/redx reuse
    }
  } else if (wg < 96) {
    // ---------------- layer 2 (combined K=1024 GEMM) ----------------
    const int j2 = wg - 32;
    const int ub2 = j2 >> 2, g = j2 & 3;
    const int U0 = ub2 * 32;
    const int bb = g * 16 + l15;
    const int kh = w;                     // 0,1: wih2 halves; 2,3: whh2 halves
    const float* src = (kh < 2) ? wih2 : whh2;
    const int koff = (kh & 1) * 256;      // K-offset within the 512-dim matrix
    bf16x8 whf[3][2][8];                  // 192 VGPR resident weights
#pragma unroll
    for (int gg = 0; gg < 3; ++gg)
#pragma unroll
      for (int m = 0; m < 2; ++m)
#pragma unroll
        for (int c = 0; c < 8; ++c)
          whf[gg][m][c] = cvt8(src + (size_t)(gg * kH + U0 + m * 16 + l15) * kH
                               + koff + c * 32 + q * 8);
    if (tid < 32) {                       // stage biases once
      int u = U0 + tid;
      sbias[0][tid] = bih2[u]          + bhh2[u];
      sbias[1][tid] = bih2[kH + u]     + bhh2[kH + u];
      sbias[2][tid] = bih2[2 * kH + u];
      sbias[3][tid] = bhh2[2 * kH + u];
    }
    float h2l[2][4];
#pragma unroll
    for (int m = 0; m < 2; ++m)
#pragma unroll
      for (int r = 0; r < 4; ++r) h2l[m][r] = 0.0f;
    __syncthreads();
    const bool upd = (kh == 0);
    int bound = 0;
    for (int k = 1; k <= kT; ++k) {
      const int t3 = k % 3, t3p = (k - 1) % 3;
      const u16* base; u32 pat;
      if (kh < 2) { base = h1b + (k & 3) * kBH;       pat = pat3(t3);  }
      else        { base = h2b + ((k - 1) & 3) * kBH; pat = pat3(t3p); }
      bf16x8 ch[8];
      dataD<8>(base + (size_t)bb * kH + koff + q * 8, pat, ch);
      f32x4 a[3][2];
#pragma unroll
      for (int gg = 0; gg < 3; ++gg)
#pragma unroll
        for (int m = 0; m < 2; ++m) a[gg][m] = {0,0,0,0};
#pragma unroll
      for (int m = 0; m < 2; ++m)
#pragma unroll
        for (int c = 0; c < 8; ++c) {
          a[0][m] = mfma(whf[0][m][c], ch[c], a[0][m]);
          a[1][m] = mfma(whf[1][m][c], ch[c], a[1][m]);
          a[2][m] = mfma(whf[2][m][c], ch[c], a[2][m]);
        }
      if (kh != 0) {
        const int s = kh - 1;             // kh1 -> gi-half2, kh2/3 -> gh halves
#pragma unroll
        for (int gg = 0; gg < 3; ++gg)
#pragma unroll
          for (int m = 0; m < 2; ++m)
#pragma unroll
            for (int r = 0; r < 4; ++r) red[s][gg][m][lane][r] = a[gg][m][r];
      } else {
        throttle(ctl, 64 + g, lane < 1, k, bound);   // h2 anti-dep (OUT)
      }
      __syncthreads();
      if (tid == 0) stflag(ctl, j2, k);   // all 4 waves fetch-verified tick k
      if (upd) {
#pragma unroll
        for (int m = 0; m < 2; ++m) {
          float hnew[4];
#pragma unroll
          for (int r = 0; r < 4; ++r) {
            float gi0 = a[0][m][r] + red[0][0][m][lane][r];
            float gi1 = a[1][m][r] + red[0][1][m][lane][r];
            float gi2 = a[2][m][r] + red[0][2][m][lane][r];
            float gh0 = red[1][0][m][lane][r] + red[2][0][m][lane][r];
            float gh1 = red[1][1][m][lane][r] + red[2][1][m][lane][r];
            float gh2 = red[1][2][m][lane][r] + red[2][2][m][lane][r];
            int uu = m * 16 + q * 4 + r;
            float rr = sigf(gi0 + gh0 + sbias[0][uu]);
            float zz = sigf(gi1 + gh1 + sbias[1][uu]);
            float nn = tanhf_(gi2 + sbias[2][uu] + rr * (gh2 + sbias[3][uu]));
            float h  = (1.0f - zz) * nn + zz * h2l[m][r];
            h2l[m][r] = h; hnew[r] = h;
          }
          st_h(h2b + (k & 3) * kBH + (size_t)bb * kH + U0 + m * 16 + q * 4, hnew, t3);
        }
      }
      __syncthreads();                    // guards red reuse
    }
  } else {
    // ---------------- output head ----------------
    const int g3 = wg - 96;
    const int bb = g3 * 16 + l15;
    const int mat = w & 1, khh = w >> 1;  // matrix x K-half
    const float* wsel = mat ? wo2 : wo1;
    bf16x8 zf = {0,0,0,0,0,0,0,0};
    bf16x8 wof[2][8];
#pragma unroll
    for (int t = 0; t < 2; ++t)
#pragma unroll
      for (int c = 0; c < 8; ++c) {
        int row = t * 16 + l15;
        wof[t][c] = (row < kO) ? cvt8(wsel + (size_t)row * kH + khh * 256 + c * 32 + q * 8) : zf;
      }
    float bv1[2][4], bv2[2][4];
#pragma unroll
    for (int t = 0; t < 2; ++t)
#pragma unroll
      for (int r = 0; r < 4; ++r) {
        int o = t * 16 + q * 4 + r;
        bv1[t][r] = (o < kO) ? bo1[o] : 0.0f;
        bv2[t][r] = (o < kO) ? bo2[o] : 0.0f;
      }
    const bool fin = (mat == 0 && khh == 0);
    const u16* slab = mat ? h2b : h1b;
    for (int k = 1; k <= kT; ++k) {
      const u32 pat = pat3(k % 3);
      bf16x8 ch[8];
      dataD<8>(slab + (k & 3) * kBH + (size_t)bb * kH + khh * 256 + q * 8, pat, ch);
      f32x4 a0 = {0,0,0,0}, a1 = {0,0,0,0};
#pragma unroll
      for (int c = 0; c < 8; ++c) {
        a0 = mfma(wof[0][c], ch[c], a0);
        a1 = mfma(wof[1][c], ch[c], a1);
      }
      if (!fin) {
        const int s = mat * 2 + khh - 1;  // (0,1)->0 (1,0)->1 (1,1)->2
#pragma unroll
        for (int r = 0; r < 4; ++r) {
          red[s][0][0][lane][r] = a0[r];
          red[s][0][1][lane][r] = a1[r];
        }
      }
      __syncthreads();
      if (tid == 0) stflag(ctl, 64 + g3, k);   // h1[k] & h2[k] fetch-verified
      if (fin) {
#pragma unroll
        for (int t = 0; t < 2; ++t) {
          int o0 = t * 16 + q * 4;
          if (o0 < kO) {
            f32x4 av = (t == 0) ? a0 : a1;
            float4 ov;
            ov.x = tanhf_(av[0] + red[0][0][t][lane][0] + bv1[t][0]) +
                   tanhf_(red[1][0][t][lane][0] + red[2][0][t][lane][0] + bv2[t][0]);
            ov.y = tanhf_(av[1] + red[0][0][t][lane][1] + bv1[t][1]) +
                   tanhf_(red[1][0][t][lane][1] + red[2][0][t][lane][1] + bv2[t][1]);
            ov.z = tanhf_(av[2] + red[0][0][t][lane][2] + bv1[t][2]) +
                   tanhf_(red[1][0][t][lane][2] + red[2][0][t][lane][2] + bv2[t][2]);
            ov.w = tanhf_(av[3] + red[0][0][t][lane][3] + bv1[t][3]) +
                   tanhf_(red[1][0][t][lane][3] + red[2][0][t][lane][3] + bv2[t][3]);
            *reinterpret_cast<float4*>(out + ((size_t)bb * kT + (k - 1)) * kO + o0) = ov;
          }
        }
      }
      __syncthreads();                    // guards red reuse
    }
  }
}

extern "C" void kernel_launch(void* const* d_in, const int* in_sizes, int n_in,
                              void* d_out, int out_size, void* d_ws, size_t ws_size,
                              hipStream_t stream) {
  (void)in_sizes; (void)n_in; (void)out_size; (void)ws_size;
  // zero h buffers + control page; invalid-tag init for buf 3 of h1 & h2
  hipMemsetAsync(d_ws, 0, kBarOff + 1024, stream);
  hipMemsetAsync((char*)d_ws + 3u * kBH * 2u, 0x01, kBH * 2u, stream);  // h1 buf3
  hipMemsetAsync((char*)d_ws + 7u * kBH * 2u, 0x01, kBH * 2u, stream);  // h2 buf3
  const float* x    = (const float*)d_in[0];
  const float* wih1 = (const float*)d_in[1];
  const float* whh1 = (const float*)d_in[2];
  const float* bih1 = (const float*)d_in[3];
  const float* bhh1 = (const float*)d_in[4];
  const float* wih2 = (const float*)d_in[5];
  const float* whh2 = (const float*)d_in[6];
  const float* bih2 = (const float*)d_in[7];
  const float* bhh2 = (const float*)d_in[8];
  const float* wo1  = (const float*)d_in[9];
  const float* bo1  = (const float*)d_in[10];
  const float* wo2  = (const float*)d_in[11];
  const float* bo2  = (const float*)d_in[12];
  float* out  = (float*)d_out;
  u16* hbuf   = (u16*)d_ws;
  int* ctl    = (int*)((char*)d_ws + kBarOff);
  stackgru<<<dim3(kNWG), dim3(256), 0, stream>>>(
      x, wih1, whh1, bih1, bhh1, wih2, whh2, bih2, bhh2,
      wo1, bo1, wo2, bo2, out, hbuf, ctl);
}